// Round 1
// baseline (1532.618 us; speedup 1.0000x reference)
//
#include <hip/hip_runtime.h>

#define NN 16384
#define FIN 512
#define FOUT 256

typedef __attribute__((ext_vector_type(8))) short short8;
typedef __attribute__((ext_vector_type(4))) float floatx4;

static __device__ __forceinline__ unsigned short f2bf(float f) {
  unsigned int u = __float_as_uint(f);
  return (unsigned short)((u + 0x7fffu + ((u >> 16) & 1u)) >> 16);  // RNE
}

static __device__ __forceinline__ void gld_lds16(const void* g, void* l) {
  __builtin_amdgcn_global_load_lds(
      (__attribute__((address_space(1))) void*)(g),
      (__attribute__((address_space(3))) void*)(l),
      16, 0, 0);
}

// ---------------------------------------------------------------------------
// Kernel 1: Gt[j][i] = hat_d[i] * sum_k feature[i,k] * W[j,k]   (bf16 out)
// M-dim = j (A-op = W [256][512] row-major = [M][K]),
// N-dim = i (B-op = feature [16384][512] row-major = [N][K], i.e. B^T form).
// Block tile: 64 j x 256 i, K=512 in BK=32 steps. Grid = 4 * 64 = 256 blocks.
// ---------------------------------------------------------------------------
__global__ __launch_bounds__(256, 2)
void k1_gt(const float* __restrict__ feat, const float* __restrict__ Wm,
           const float* __restrict__ hat_d, unsigned short* __restrict__ Gt) {
  __shared__ unsigned short Wsm[64 * 40];    // [64][32] padded to 40
  __shared__ unsigned short Fsm[256 * 40];   // [256][32] padded to 40
  const int bx = blockIdx.x;
  const int j0 = (bx & 3) * 64;
  const int i0 = (bx >> 2) * 256;
  const int t = threadIdx.x;
  const int wave = t >> 6;
  const int ln = t & 15;
  const int quad = (t >> 4) & 3;
  const int arow = t >> 2, ac = t & 3;

  floatx4 acc[4][4];
  for (int a = 0; a < 4; ++a)
    for (int n = 0; n < 4; ++n) acc[a][n] = (floatx4){0.f, 0.f, 0.f, 0.f};

  for (int k0 = 0; k0 < FIN; k0 += 32) {
    // stage W tile [64][32] -> Wsm (fp32 -> bf16)
    {
      const float* src = Wm + (size_t)(j0 + arow) * FIN + k0 + ac * 8;
      floatx4 v0 = *(const floatx4*)(src);
      floatx4 v1 = *(const floatx4*)(src + 4);
      short8 pk;
      for (int e = 0; e < 4; ++e) {
        pk[e] = (short)f2bf(v0[e]);
        pk[4 + e] = (short)f2bf(v1[e]);
      }
      *(short8*)&Wsm[arow * 40 + ac * 8] = pk;
    }
    // stage feature tile [256][32] -> Fsm
    for (int r = 0; r < 4; ++r) {
      const int u = r * 256 + t;
      const int n = u >> 2, c = u & 3;
      const float* src = feat + (size_t)(i0 + n) * FIN + k0 + c * 8;
      floatx4 v0 = *(const floatx4*)(src);
      floatx4 v1 = *(const floatx4*)(src + 4);
      short8 pk;
      for (int e = 0; e < 4; ++e) {
        pk[e] = (short)f2bf(v0[e]);
        pk[4 + e] = (short)f2bf(v1[e]);
      }
      *(short8*)&Fsm[n * 40 + c * 8] = pk;
    }
    __syncthreads();
    short8 aF[4], bF[4];
    for (int mt = 0; mt < 4; ++mt)
      aF[mt] = *(const short8*)&Wsm[(mt * 16 + ln) * 40 + quad * 8];
    for (int nt = 0; nt < 4; ++nt)
      bF[nt] = *(const short8*)&Fsm[(wave * 64 + nt * 16 + ln) * 40 + quad * 8];
    for (int mt = 0; mt < 4; ++mt)
      for (int nt = 0; nt < 4; ++nt)
        acc[mt][nt] = __builtin_amdgcn_mfma_f32_16x16x32_bf16(
            aF[mt], bF[nt], acc[mt][nt], 0, 0, 0);
    __syncthreads();
  }

  // epilogue: apply hat_d (per output column i), store bf16 Gt[j][i]
  float hd[4];
  int icol[4];
  for (int nt = 0; nt < 4; ++nt) {
    icol[nt] = i0 + wave * 64 + nt * 16 + ln;
    hd[nt] = hat_d[icol[nt]];
  }
  for (int mt = 0; mt < 4; ++mt)
    for (int r = 0; r < 4; ++r) {
      const int j = j0 + mt * 16 + quad * 4 + r;
      for (int nt = 0; nt < 4; ++nt)
        Gt[(size_t)j * NN + icol[nt]] = f2bf(acc[mt][nt][r] * hd[nt]);
    }
}

// ---------------------------------------------------------------------------
// Kernel 2: part[kh][i][j] = sum_{t in K-half kh} (A+I)[i][t] * G[t][j]
// A fp32 [16384][16384] row-major, converted to bf16 in staging (+1 on diag).
// Gt bf16 [256][16384] (B^T layout). Block tile: M=64 x N=256, split-K=2.
// Grid = 256 * 2 = 512 blocks (2 blocks/CU). BK=32, 256 K-iters.
// ---------------------------------------------------------------------------
__global__ __launch_bounds__(256, 2)
void k2_agemm(const float* __restrict__ A, const unsigned short* __restrict__ Gt,
              float* __restrict__ part) {
  __shared__ unsigned short Asm[64 * 40];    // [64][32] padded to 40 (ds_write path)
  __shared__ unsigned short Gsm[256 * 32];   // [256][32] unpadded (global_load_lds)
  const int bx = blockIdx.x;
  const int kh = bx & 1;
  const int i0 = (bx >> 1) * 64;
  const int kbase = kh * (NN / 2);
  const int t = threadIdx.x;
  const int wave = t >> 6;
  const int ln = t & 15;
  const int quad = (t >> 4) & 3;
  const int arow = t >> 2, ac = t & 3;
  const int gi = i0 + arow;
  const float* Abase = A + (size_t)gi * NN + ac * 8;

  floatx4 acc[4][4];
  for (int a = 0; a < 4; ++a)
    for (int n = 0; n < 4; ++n) acc[a][n] = (floatx4){0.f, 0.f, 0.f, 0.f};

  for (int it = 0; it < (NN / 2) / 32; ++it) {
    const int k0 = kbase + it * 32;
    // ---- stage A [64][32] fp32 -> bf16, fuse identity on the diagonal ----
    {
      const float* src = Abase + k0;
      floatx4 v0 = *(const floatx4*)(src);
      floatx4 v1 = *(const floatx4*)(src + 4);
      const int d = gi - (k0 + ac * 8);
      if (d >= 0 && d < 8) {               // (A + I): rare, one hit per row
        if (d < 4) v0[d] += 1.0f;
        else       v1[d - 4] += 1.0f;
      }
      short8 pk;
      for (int e = 0; e < 4; ++e) {
        pk[e] = (short)f2bf(v0[e]);
        pk[4 + e] = (short)f2bf(v1[e]);
      }
      *(short8*)&Asm[arow * 40 + ac * 8] = pk;
    }
    // ---- stage Gt tile [256 n][32 k] via async global->LDS, 16B/lane ----
    for (int r = 0; r < 4; ++r) {
      const int u = r * 256 + t;
      const unsigned short* g = Gt + (size_t)(u >> 2) * NN + k0 + (u & 3) * 8;
      gld_lds16(g, &Gsm[(r * 256 + wave * 64) * 8]);  // wave-uniform base
    }
    __syncthreads();
    short8 aF[4], bF[4];
    for (int mt = 0; mt < 4; ++mt)
      aF[mt] = *(const short8*)&Asm[(mt * 16 + ln) * 40 + quad * 8];
    for (int nt = 0; nt < 4; ++nt)
      bF[nt] = *(const short8*)&Gsm[(wave * 64 + nt * 16 + ln) * 32 + quad * 8];
    for (int mt = 0; mt < 4; ++mt)
      for (int nt = 0; nt < 4; ++nt)
        acc[mt][nt] = __builtin_amdgcn_mfma_f32_16x16x32_bf16(
            aF[mt], bF[nt], acc[mt][nt], 0, 0, 0);
    __syncthreads();
  }

  // epilogue: write fp32 partials
  float* pout = part + (size_t)kh * NN * FOUT;
  for (int mt = 0; mt < 4; ++mt)
    for (int r = 0; r < 4; ++r) {
      const int row = i0 + mt * 16 + quad * 4 + r;
      for (int nt = 0; nt < 4; ++nt) {
        const int col = wave * 64 + nt * 16 + ln;
        pout[(size_t)row * FOUT + col] = acc[mt][nt][r];
      }
    }
}

// ---------------------------------------------------------------------------
// Kernel 3: out[i][j] = hat_d[i] * (part0[i][j] + part1[i][j]) + b[j]
// ---------------------------------------------------------------------------
__global__ __launch_bounds__(256)
void k3_out(const float* __restrict__ part, const float* __restrict__ hat_d,
            const float* __restrict__ b, float* __restrict__ out) {
  const int u = blockIdx.x * 256 + threadIdx.x;  // one float4 per thread
  const int i = u >> 6;                          // 64 float4-units per row
  const int j4 = u & 63;
  floatx4 p0 = *(const floatx4*)(part + (size_t)u * 4);
  floatx4 p1 = *(const floatx4*)(part + (size_t)NN * FOUT + (size_t)u * 4);
  floatx4 bb = *(const floatx4*)(b + j4 * 4);
  const float hd = hat_d[i];
  floatx4 o = (p0 + p1) * hd + bb;
  *(floatx4*)(out + (size_t)u * 4) = o;
}

extern "C" void kernel_launch(void* const* d_in, const int* in_sizes, int n_in,
                              void* d_out, int out_size, void* d_ws, size_t ws_size,
                              hipStream_t stream) {
  const float* A       = (const float*)d_in[0];   // [16384,16384]
  const float* hat_d   = (const float*)d_in[1];   // [16384]
  const float* feature = (const float*)d_in[2];   // [16384,512]
  const float* W       = (const float*)d_in[3];   // [256,512]
  const float* b       = (const float*)d_in[4];   // [256]
  float* out = (float*)d_out;                     // [16384,256] fp32

  // workspace layout: Gt bf16 [256][16384] (8 MiB), then partials fp32 [2][16384][256] (32 MiB)
  unsigned short* Gt = (unsigned short*)d_ws;
  float* part = (float*)((char*)d_ws + (size_t)FOUT * NN * sizeof(unsigned short));

  k1_gt<<<256, 256, 0, stream>>>(feature, W, hat_d, Gt);
  k2_agemm<<<512, 256, 0, stream>>>(A, Gt, part);
  k3_out<<<(NN * FOUT / 4) / 256, 256, 0, stream>>>(part, hat_d, b, out);
}